// Round 7
// baseline (199.440 us; speedup 1.0000x reference)
//
#include <hip/hip_runtime.h>

#define HID 64
#define NTOK 66          // VOCAB_SIZE + 2
#define SEQ 64
#define WIN0 55          // SEQ_LEN - 1 - MEMORY_SLOTS
#define NW 8
#define LDS_STRIDE 72    // ushorts per table row (144B; token -> bank-quad uniform)
#define ITERS 4          // iterations per block (rows/block = 256)
#define ROWS_PER_ITER 64 // 4 waves x 16 rows

typedef short short8 __attribute__((ext_vector_type(8)));
typedef unsigned short ushort8v __attribute__((ext_vector_type(8)));
typedef unsigned int uint4v __attribute__((ext_vector_type(4)));
typedef float float2v __attribute__((ext_vector_type(2)));
typedef float float4v __attribute__((ext_vector_type(4)));

static __device__ __forceinline__ unsigned short f2bf(float f) {
    union { float f; unsigned u; } v; v.f = f;
    unsigned r = v.u + 0x7FFFu + ((v.u >> 16) & 1u);
    return (unsigned short)(r >> 16);
}
static __device__ __forceinline__ float u2f(unsigned u) {
    union { unsigned u; float f; } v; v.u = u;
    return v.f;
}

// Kernel 1: tables T1[t][n] = b1[n] + sum_k emb[t][k]*W1[n][k]
//           T2[t][n] = 0.125 * sum_k emb[t][k]*W1[n][64+k]
// stored bf16 in ws: [2][66][64]
__global__ void build_tables(const float* __restrict__ embed,
                             const float* __restrict__ W1,
                             const float* __restrict__ b1,
                             unsigned short* __restrict__ tbl) {
    int b = blockIdx.x;      // 0..131
    int tb = b & 1;
    int t  = b >> 1;
    int n  = threadIdx.x;    // 0..63
    float acc = tb ? 0.0f : b1[n];
    const float* er = embed + t * HID;
    const float* wr = W1 + n * (2 * HID) + tb * HID;
#pragma unroll 8
    for (int k = 0; k < HID; ++k) acc += er[k] * wr[k];
    if (tb) acc *= 0.125f;
    tbl[tb * (NTOK * HID) + t * HID + n] = f2bf(acc);
}

// Build one chunk (8 consecutive k) of h[row] = relu(T1[q] + sum_j T2[w_j]).
// bf16-pair dwords unpacked to float2 {lo<<16, hi&0xFFFF0000}; float2 adds
// pair into v_pk_add_f32. T1 row initializes the accumulators.
static __device__ __forceinline__ short8 build_hfrag(
    const unsigned short* T_lds, int q, const int* w, int k0c) {
    uint4v tv = *(const uint4v*)(T_lds + q * LDS_STRIDE + k0c);
    float2v acc[4];
#pragma unroll
    for (int i = 0; i < 4; ++i) {
        acc[i].x = u2f(tv[i] << 16);
        acc[i].y = u2f(tv[i] & 0xFFFF0000u);
    }
#pragma unroll
    for (int j = 0; j < NW; ++j) {
        uint4v v2 = *(const uint4v*)(T_lds + NTOK * LDS_STRIDE + w[j] * LDS_STRIDE + k0c);
#pragma unroll
        for (int i = 0; i < 4; ++i) {
            float2v p;
            p.x = u2f(v2[i] << 16);
            p.y = u2f(v2[i] & 0xFFFF0000u);
            acc[i] += p;
        }
    }
    short8 a;
#pragma unroll
    for (int i = 0; i < 4; ++i) {
        a[2 * i]     = (short)f2bf(fmaxf(acc[i].x, 0.0f));
        a[2 * i + 1] = (short)f2bf(fmaxf(acc[i].y, 0.0f));
    }
    return a;
}

// Kernel 2: logits^T = W2 (A-op) x h^T (B-op) via mfma_f32_16x16x32_bf16.
// TLP version: grid = B/256 (8 blocks/CU resident; VGPR<=64, LDS 19456B x 8
// = 155.6KB). 4 iterations per block, depth-2 token prefetch, one barrier.
__global__ __launch_bounds__(256, 8) void fused_forward(
    const int* __restrict__ seqs,
    const int* __restrict__ qtok,
    const float* __restrict__ W2,
    const float* __restrict__ b2,
    const unsigned short* __restrict__ tbl,
    float* __restrict__ out)
{
    __shared__ unsigned short T_lds[2 * NTOK * LDS_STRIDE]; // 19008 B

    int tid  = threadIdx.x;
    int wv   = tid >> 6;
    int l    = tid & 63;
    int lrow = l & 15;          // W2 row within n-tile / batch row within tile
    int lg   = l >> 4;
    int lk8  = lg * 8;          // k offset within 32-wide K chunk

    int row0 = blockIdx.x * (ITERS * ROWS_PER_ITER) + wv * 16 + lrow;

// scalar token loads (proven-clean HBM traffic)
#define LOADT(s, t_) { \
    int row_ = row0 + (t_) * ROWS_PER_ITER; \
    q##s = qtok[row_]; \
    const int* sp_ = seqs + row_ * SEQ + WIN0; \
    _Pragma("unroll") \
    for (int j = 0; j < NW; ++j) w##s[j] = sp_[j]; \
}

// bias folded into MFMA C-operand init
#define COMPUTE(s, t_) { \
    short8 a0 = build_hfrag(T_lds, q##s, w##s, lk8); \
    short8 a1 = build_hfrag(T_lds, q##s, w##s, 32 + lk8); \
    float* op = out + (size_t)(row0 + (t_) * ROWS_PER_ITER) * HID; \
    _Pragma("unroll") \
    for (int nt = 0; nt < 4; ++nt) { \
        float4v acc = b2v[nt]; \
        acc = __builtin_amdgcn_mfma_f32_16x16x32_bf16(wfrag[nt][0], a0, acc, 0, 0, 0); \
        acc = __builtin_amdgcn_mfma_f32_16x16x32_bf16(wfrag[nt][1], a1, acc, 0, 0, 0); \
        *(float4v*)(op + nt * 16 + lg * 4) = acc; \
    } \
}

    int qA, qB;
    int wA[NW], wB[NW];

    // ---- (1) iter 0/1 token loads: HBM latency hides under W2+fill+barrier ----
    LOADT(A, 0);
    LOADT(B, 1);

    // ---- (2) W2 A-fragments in registers (whole 64x64) + b2 float4 ----
    short8  wfrag[4][2];
    float4v b2v[4];
#pragma unroll
    for (int nt = 0; nt < 4; ++nt) {
        b2v[nt] = *(const float4v*)(b2 + nt * 16 + lg * 4);
#pragma unroll
        for (int kc = 0; kc < 2; ++kc) {
            const float* wp = W2 + (nt * 16 + lrow) * HID + kc * 32 + lk8;
            short8 f;
#pragma unroll
            for (int j = 0; j < 8; ++j) f[j] = (short)f2bf(wp[j]);
            wfrag[nt][kc] = f;
        }
    }

    // ---- (3) fill LDS tables (16B chunks; row stride 144B) ----
    for (int i = tid; i < 2 * NTOK * (HID / 8); i += 256) {
        int tbi = i / (NTOK * 8);
        int rem = i - tbi * (NTOK * 8);
        int t   = rem >> 3;
        int kq  = (rem & 7) << 3;
        *(ushort8v*)(T_lds + tbi * (NTOK * LDS_STRIDE) + t * LDS_STRIDE + kq) =
            *(const ushort8v*)(tbl + tbi * (NTOK * HID) + t * HID + kq);
    }
    __syncthreads();

    // ---- (4) 4 iterations, depth-2 token pipeline (all indices static) ----
    COMPUTE(A, 0); LOADT(A, 2);
    COMPUTE(B, 1); LOADT(B, 3);
    COMPUTE(A, 2);
    COMPUTE(B, 3);

#undef LOADT
#undef COMPUTE
}

extern "C" void kernel_launch(void* const* d_in, const int* in_sizes, int n_in,
                              void* d_out, int out_size, void* d_ws, size_t ws_size,
                              hipStream_t stream) {
    const int*   seqs  = (const int*)d_in[0];
    const int*   qtok  = (const int*)d_in[1];
    const float* embed = (const float*)d_in[2];
    const float* W1    = (const float*)d_in[3];
    const float* b1    = (const float*)d_in[4];
    const float* W2    = (const float*)d_in[5];
    const float* b2    = (const float*)d_in[6];
    float* out = (float*)d_out;
    unsigned short* tbl = (unsigned short*)d_ws;

    int B = in_sizes[0] / SEQ;

    build_tables<<<NTOK * 2, HID, 0, stream>>>(embed, W1, b1, tbl);

    int grid = B / (ITERS * ROWS_PER_ITER);
    fused_forward<<<grid, 256, 0, stream>>>(seqs, qtok, W2, b2, tbl, out);
}

// Round 8
// 59.304 us; speedup vs baseline: 3.3630x; 3.3630x over previous
//
#include <hip/hip_runtime.h>

#define HID 64
#define NTOK 66          // VOCAB_SIZE + 2
#define SEQ 64
#define WIN0 55          // SEQ_LEN - 1 - MEMORY_SLOTS
#define NW 8
#define LDS_STRIDE 72    // ushorts per table row (144B; token -> bank-quad uniform)
#define ITERS 4          // iterations per block (rows/block = 256, grid = 2048)
#define ROWS_PER_ITER 64 // 4 waves x 16 rows

typedef short short8 __attribute__((ext_vector_type(8)));
typedef unsigned short ushort8v __attribute__((ext_vector_type(8)));
typedef unsigned int uint4v __attribute__((ext_vector_type(4)));
typedef float float2v __attribute__((ext_vector_type(2)));
typedef float float4v __attribute__((ext_vector_type(4)));

static __device__ __forceinline__ unsigned short f2bf(float f) {
    union { float f; unsigned u; } v; v.f = f;
    unsigned r = v.u + 0x7FFFu + ((v.u >> 16) & 1u);
    return (unsigned short)(r >> 16);
}
static __device__ __forceinline__ float u2f(unsigned u) {
    union { unsigned u; float f; } v; v.u = u;
    return v.f;
}

// Kernel 1: tables T1[t][n] = b1[n] + sum_k emb[t][k]*W1[n][k]
//           T2[t][n] = 0.125 * sum_k emb[t][k]*W1[n][64+k]
// stored bf16 in ws: [2][66][64]
__global__ void build_tables(const float* __restrict__ embed,
                             const float* __restrict__ W1,
                             const float* __restrict__ b1,
                             unsigned short* __restrict__ tbl) {
    int b = blockIdx.x;      // 0..131
    int tb = b & 1;
    int t  = b >> 1;
    int n  = threadIdx.x;    // 0..63
    float acc = tb ? 0.0f : b1[n];
    const float* er = embed + t * HID;
    const float* wr = W1 + n * (2 * HID) + tb * HID;
#pragma unroll 8
    for (int k = 0; k < HID; ++k) acc += er[k] * wr[k];
    if (tb) acc *= 0.125f;
    tbl[tb * (NTOK * HID) + t * HID + n] = f2bf(acc);
}

// Build one chunk (8 consecutive k) of h[row] = relu(T1[q] + sum_j T2[w_j]).
// bf16-pair dwords unpacked to float2 {lo<<16, hi&0xFFFF0000}; float2 adds
// pair into v_pk_add_f32. T1 row initializes the accumulators.
static __device__ __forceinline__ short8 build_hfrag(
    const unsigned short* T_lds, int q, const int* w, int k0c) {
    uint4v tv = *(const uint4v*)(T_lds + q * LDS_STRIDE + k0c);
    float2v acc[4];
#pragma unroll
    for (int i = 0; i < 4; ++i) {
        acc[i].x = u2f(tv[i] << 16);
        acc[i].y = u2f(tv[i] & 0xFFFF0000u);
    }
#pragma unroll
    for (int j = 0; j < NW; ++j) {
        uint4v v2 = *(const uint4v*)(T_lds + NTOK * LDS_STRIDE + w[j] * LDS_STRIDE + k0c);
#pragma unroll
        for (int i = 0; i < 4; ++i) {
            float2v p;
            p.x = u2f(v2[i] << 16);
            p.y = u2f(v2[i] & 0xFFFF0000u);
            acc[i] += p;
        }
    }
    short8 a;
#pragma unroll
    for (int i = 0; i < 4; ++i) {
        a[2 * i]     = (short)f2bf(fmaxf(acc[i].x, 0.0f));
        a[2 * i + 1] = (short)f2bf(fmaxf(acc[i].y, 0.0f));
    }
    return a;
}

// Kernel 2: logits^T = W2 (A-op) x h^T (B-op) via mfma_f32_16x16x32_bf16.
// TLP via grid: 2048 blocks -> 8 blocks/CU resident (VGPR=64 from (256,4)
// codegen -- round 5 evidence; LDS 19456B x 8 = 155.6KB <= 160KB).
// launch_bounds' 2nd arg only constrains the allocator, NOT residency:
// (256,8) forced VGPR=32 and spilled (round 7); (256,4) gives 64, no spill.
__global__ __launch_bounds__(256, 4) void fused_forward(
    const int* __restrict__ seqs,
    const int* __restrict__ qtok,
    const float* __restrict__ W2,
    const float* __restrict__ b2,
    const unsigned short* __restrict__ tbl,
    float* __restrict__ out)
{
    __shared__ unsigned short T_lds[2 * NTOK * LDS_STRIDE]; // 19008 B

    int tid  = threadIdx.x;
    int wv   = tid >> 6;
    int l    = tid & 63;
    int lrow = l & 15;          // W2 row within n-tile / batch row within tile
    int lg   = l >> 4;
    int lk8  = lg * 8;          // k offset within 32-wide K chunk

    int row0 = blockIdx.x * (ITERS * ROWS_PER_ITER) + wv * 16 + lrow;

// scalar token loads (proven-clean HBM traffic)
#define LOADT(s, t_) { \
    int row_ = row0 + (t_) * ROWS_PER_ITER; \
    q##s = qtok[row_]; \
    const int* sp_ = seqs + row_ * SEQ + WIN0; \
    _Pragma("unroll") \
    for (int j = 0; j < NW; ++j) w##s[j] = sp_[j]; \
}

// bias folded into MFMA C-operand init
#define COMPUTE(s, t_) { \
    short8 a0 = build_hfrag(T_lds, q##s, w##s, lk8); \
    short8 a1 = build_hfrag(T_lds, q##s, w##s, 32 + lk8); \
    float* op = out + (size_t)(row0 + (t_) * ROWS_PER_ITER) * HID; \
    _Pragma("unroll") \
    for (int nt = 0; nt < 4; ++nt) { \
        float4v acc = b2v[nt]; \
        acc = __builtin_amdgcn_mfma_f32_16x16x32_bf16(wfrag[nt][0], a0, acc, 0, 0, 0); \
        acc = __builtin_amdgcn_mfma_f32_16x16x32_bf16(wfrag[nt][1], a1, acc, 0, 0, 0); \
        *(float4v*)(op + nt * 16 + lg * 4) = acc; \
    } \
}

    int qA, qB;
    int wA[NW], wB[NW];

    // ---- (1) iter 0/1 token loads: HBM latency hides under W2+fill+barrier ----
    LOADT(A, 0);
    LOADT(B, 1);

    // ---- (2) W2 A-fragments in registers (whole 64x64) + b2 float4 ----
    short8  wfrag[4][2];
    float4v b2v[4];
#pragma unroll
    for (int nt = 0; nt < 4; ++nt) {
        b2v[nt] = *(const float4v*)(b2 + nt * 16 + lg * 4);
#pragma unroll
        for (int kc = 0; kc < 2; ++kc) {
            const float* wp = W2 + (nt * 16 + lrow) * HID + kc * 32 + lk8;
            short8 f;
#pragma unroll
            for (int j = 0; j < 8; ++j) f[j] = (short)f2bf(wp[j]);
            wfrag[nt][kc] = f;
        }
    }

    // ---- (3) fill LDS tables (16B chunks; row stride 144B) ----
    for (int i = tid; i < 2 * NTOK * (HID / 8); i += 256) {
        int tbi = i / (NTOK * 8);
        int rem = i - tbi * (NTOK * 8);
        int t   = rem >> 3;
        int kq  = (rem & 7) << 3;
        *(ushort8v*)(T_lds + tbi * (NTOK * LDS_STRIDE) + t * LDS_STRIDE + kq) =
            *(const ushort8v*)(tbl + tbi * (NTOK * HID) + t * HID + kq);
    }
    __syncthreads();

    // ---- (4) 4 iterations, depth-2 token pipeline (all indices static) ----
    COMPUTE(A, 0); LOADT(A, 2);
    COMPUTE(B, 1); LOADT(B, 3);
    COMPUTE(A, 2);
    COMPUTE(B, 3);

#undef LOADT
#undef COMPUTE
}

extern "C" void kernel_launch(void* const* d_in, const int* in_sizes, int n_in,
                              void* d_out, int out_size, void* d_ws, size_t ws_size,
                              hipStream_t stream) {
    const int*   seqs  = (const int*)d_in[0];
    const int*   qtok  = (const int*)d_in[1];
    const float* embed = (const float*)d_in[2];
    const float* W1    = (const float*)d_in[3];
    const float* b1    = (const float*)d_in[4];
    const float* W2    = (const float*)d_in[5];
    const float* b2    = (const float*)d_in[6];
    float* out = (float*)d_out;
    unsigned short* tbl = (unsigned short*)d_ws;

    int B = in_sizes[0] / SEQ;

    build_tables<<<NTOK * 2, HID, 0, stream>>>(embed, W1, b1, tbl);

    int grid = B / (ITERS * ROWS_PER_ITER);
    fused_forward<<<grid, 256, 0, stream>>>(seqs, qtok, W2, b2, tbl, out);
}

// Round 9
// 50.495 us; speedup vs baseline: 3.9497x; 1.1745x over previous
//
#include <hip/hip_runtime.h>

#define HID 64
#define NTOK 66          // VOCAB_SIZE + 2
#define SEQ 64
#define WIN0 55          // SEQ_LEN - 1 - MEMORY_SLOTS
#define NW 8
#define LDS_STRIDE 72    // ushorts per table row (144B; token -> bank-quad uniform)
#define ITERS 8          // iterations per block (rows/block = 512, grid = 1024)
#define ROWS_PER_ITER 64 // 4 waves x 16 rows

typedef _Float16 half8 __attribute__((ext_vector_type(8)));
typedef unsigned short ushort8v __attribute__((ext_vector_type(8)));
typedef float float4v __attribute__((ext_vector_type(4)));

static __device__ __forceinline__ unsigned short f2h(float f) {
    _Float16 h = (_Float16)f;
    union { _Float16 h; unsigned short u; } v; v.h = h;
    return v.u;
}

// Kernel 1: tables T1[t][n] = b1[n] + sum_k emb[t][k]*W1[n][k]
//           T2[t][n] = 0.125 * sum_k emb[t][k]*W1[n][64+k]
// stored F16 in ws: [2][66][64]  (f16: 10 mantissa bits > bf16's 7; values O(1))
__global__ void build_tables(const float* __restrict__ embed,
                             const float* __restrict__ W1,
                             const float* __restrict__ b1,
                             unsigned short* __restrict__ tbl) {
    int b = blockIdx.x;      // 0..131
    int tb = b & 1;
    int t  = b >> 1;
    int n  = threadIdx.x;    // 0..63
    float acc = tb ? 0.0f : b1[n];
    const float* er = embed + t * HID;
    const float* wr = W1 + n * (2 * HID) + tb * HID;
#pragma unroll 8
    for (int k = 0; k < HID; ++k) acc += er[k] * wr[k];
    if (tb) acc *= 0.125f;
    tbl[tb * (NTOK * HID) + t * HID + n] = f2h(acc);
}

// Build one chunk (8 consecutive k) of h[row] = relu(T1[q] + sum_j T2[w_j]).
// Entirely in packed f16: ds_read_b128 -> v_pk_add_f16 -> pk max -> MFMA A/B
// operand directly. No unpack/convert in the hot loop.
static __device__ __forceinline__ half8 build_hfrag(
    const unsigned short* T_lds, int q, const int* w, int k0c) {
    half8 acc = *(const half8*)(T_lds + q * LDS_STRIDE + k0c);
#pragma unroll
    for (int j = 0; j < NW; ++j)
        acc += *(const half8*)(T_lds + NTOK * LDS_STRIDE + w[j] * LDS_STRIDE + k0c);
    half8 z = (half8)(_Float16)0;
    return __builtin_elementwise_max(acc, z);
}

// Kernel 2: logits^T = W2 (A-op) x h^T (B-op) via mfma_f32_16x16x32_f16.
// Round-5 skeleton: grid=1024, 8 iters/block, depth-2 token prefetch,
// one barrier. launch_bounds(256,4): (256,8) forces VGPR=32 and spills
// (round 7); natural codegen here is 64 VGPR, zero spill (round 5).
__global__ __launch_bounds__(256, 4) void fused_forward(
    const int* __restrict__ seqs,
    const int* __restrict__ qtok,
    const float* __restrict__ W2,
    const float* __restrict__ b2,
    const unsigned short* __restrict__ tbl,
    float* __restrict__ out)
{
    __shared__ unsigned short T_lds[2 * NTOK * LDS_STRIDE]; // 19008 B

    int tid  = threadIdx.x;
    int wv   = tid >> 6;
    int l    = tid & 63;
    int lrow = l & 15;          // W2 row within n-tile / batch row within tile
    int lg   = l >> 4;
    int lk8  = lg * 8;          // k offset within 32-wide K chunk

    int row0 = blockIdx.x * (ITERS * ROWS_PER_ITER) + wv * 16 + lrow;

// scalar token loads (proven-clean HBM traffic)
#define LOADT(s, t_) { \
    int row_ = row0 + (t_) * ROWS_PER_ITER; \
    q##s = qtok[row_]; \
    const int* sp_ = seqs + row_ * SEQ + WIN0; \
    _Pragma("unroll") \
    for (int j = 0; j < NW; ++j) w##s[j] = sp_[j]; \
}

// bias folded into MFMA C-operand init
#define COMPUTE(s, t_) { \
    half8 a0 = build_hfrag(T_lds, q##s, w##s, lk8); \
    half8 a1 = build_hfrag(T_lds, q##s, w##s, 32 + lk8); \
    float* op = out + (size_t)(row0 + (t_) * ROWS_PER_ITER) * HID; \
    _Pragma("unroll") \
    for (int nt = 0; nt < 4; ++nt) { \
        float4v acc = b2v[nt]; \
        acc = __builtin_amdgcn_mfma_f32_16x16x32_f16(wfrag[nt][0], a0, acc, 0, 0, 0); \
        acc = __builtin_amdgcn_mfma_f32_16x16x32_f16(wfrag[nt][1], a1, acc, 0, 0, 0); \
        *(float4v*)(op + nt * 16 + lg * 4) = acc; \
    } \
}

    int qA, qB;
    int wA[NW], wB[NW];

    // ---- (1) iter 0/1 token loads: HBM latency hides under W2+fill+barrier ----
    LOADT(A, 0);
    LOADT(B, 1);

    // ---- (2) W2 A-fragments in registers (whole 64x64, f16) + b2 float4 ----
    half8   wfrag[4][2];
    float4v b2v[4];
#pragma unroll
    for (int nt = 0; nt < 4; ++nt) {
        b2v[nt] = *(const float4v*)(b2 + nt * 16 + lg * 4);
#pragma unroll
        for (int kc = 0; kc < 2; ++kc) {
            const float* wp = W2 + (nt * 16 + lrow) * HID + kc * 32 + lk8;
            half8 f;
#pragma unroll
            for (int j = 0; j < 8; ++j) f[j] = (_Float16)wp[j];
            wfrag[nt][kc] = f;
        }
    }

    // ---- (3) fill LDS tables (16B chunks; row stride 144B) ----
    for (int i = tid; i < 2 * NTOK * (HID / 8); i += 256) {
        int tbi = i / (NTOK * 8);
        int rem = i - tbi * (NTOK * 8);
        int t   = rem >> 3;
        int kq  = (rem & 7) << 3;
        *(ushort8v*)(T_lds + tbi * (NTOK * LDS_STRIDE) + t * LDS_STRIDE + kq) =
            *(const ushort8v*)(tbl + tbi * (NTOK * HID) + t * HID + kq);
    }
    __syncthreads();

    // ---- (4) 8 iterations, depth-2 token pipeline (all indices static) ----
    COMPUTE(A, 0); LOADT(A, 2);
    COMPUTE(B, 1); LOADT(B, 3);
    COMPUTE(A, 2); LOADT(A, 4);
    COMPUTE(B, 3); LOADT(B, 5);
    COMPUTE(A, 4); LOADT(A, 6);
    COMPUTE(B, 5); LOADT(B, 7);
    COMPUTE(A, 6);
    COMPUTE(B, 7);

#undef LOADT
#undef COMPUTE
}

extern "C" void kernel_launch(void* const* d_in, const int* in_sizes, int n_in,
                              void* d_out, int out_size, void* d_ws, size_t ws_size,
                              hipStream_t stream) {
    const int*   seqs  = (const int*)d_in[0];
    const int*   qtok  = (const int*)d_in[1];
    const float* embed = (const float*)d_in[2];
    const float* W1    = (const float*)d_in[3];
    const float* b1    = (const float*)d_in[4];
    const float* W2    = (const float*)d_in[5];
    const float* b2    = (const float*)d_in[6];
    float* out = (float*)d_out;
    unsigned short* tbl = (unsigned short*)d_ws;

    int B = in_sizes[0] / SEQ;

    build_tables<<<NTOK * 2, HID, 0, stream>>>(embed, W1, b1, tbl);

    int grid = B / (ITERS * ROWS_PER_ITER);
    fused_forward<<<grid, 256, 0, stream>>>(seqs, qtok, W2, b2, tbl, out);
}